// Round 5
// baseline (92.970 us; speedup 1.0000x reference)
//
#include <hip/hip_runtime.h>
#include <hip/hip_bf16.h>

// Problem constants (DynamicGraphPruning: B=8, H=W=128, C=256, PROJ=128)
#define Bn   8
#define Ln   16384     // H*W
#define Cn   256
#define Pn   128       // PROJ
#define En   65024     // 4*127*128 grid edges
#define LN_EPSf 1e-5f
#define TROWS 64       // rows per tile
#define TPB   4        // tiles per block (512 blocks x 4 x 64 rows = 131072)

typedef __attribute__((ext_vector_type(8))) short short8;   // bf16x8 MFMA frag
typedef __attribute__((ext_vector_type(4))) float f32x4;    // MFMA accum frag

__device__ __forceinline__ float bf2f(unsigned short u) {
    union { unsigned int i; float f; } v;
    v.i = ((unsigned int)u) << 16;
    return v.f;
}
__device__ __forceinline__ unsigned short f2bf(float x) {
    __hip_bfloat16 h = __float2bfloat16(x);   // RNE
    return *reinterpret_cast<unsigned short*>(&h);
}

// ---------------------------------------------------------------------------
// Kernel 0: W (C x P, f32) -> Wt (P x C, bf16) via LDS transpose. grid=4.
__global__ __launch_bounds__(256)
void wt_prep(const float* __restrict__ W, __hip_bfloat16* __restrict__ Wt)
{
    __shared__ float tile[64 * 128];          // 32 KB: 64 c-rows x 128 p
    const int t  = threadIdx.x;
    const int c0 = blockIdx.x * 64;

    const float* src = W + (size_t)c0 * Pn;
#pragma unroll
    for (int i = 0; i < 32; i++) tile[t + i * 256] = src[t + i * 256];
    __syncthreads();

    const int p  = t >> 1;
    const int ch = (t & 1) * 32;
    __hip_bfloat16* dst = Wt + (size_t)p * Cn + c0 + ch;
#pragma unroll
    for (int c = 0; c < 32; c++) {
        unsigned short v = f2bf(tile[(ch + c) * Pn + p]);
        *reinterpret_cast<unsigned short*>(dst + c) = v;
    }
}

// ---------------------------------------------------------------------------
// Kernel 1: h = F @ W + b; LayerNorm; L2-normalize -> sem (bf16).
// Swapped-operand MFMA: D = Wt_frag * F_frag so D's COLUMN = feature row.
// Block: 512 thr = 8 waves = 4 row-groups (rg) x 2 p-halves (ph).
// Persistent: 512 blocks x TPB=4 tiles of TROWS=64 rows, double-buffered LDS,
// next-tile F loads issued BEFORE compute (compute phase has zero VMEM reads:
// Wt fragments live in 128 VGPRs, loaded once per block).
__global__ __launch_bounds__(512, 2)
void proj_mfma2(const float* __restrict__ F,
                const __hip_bfloat16* __restrict__ Wt,
                const float* __restrict__ bp, const float* __restrict__ gam,
                const float* __restrict__ bet, __hip_bfloat16* __restrict__ sem)
{
    __shared__ char  Fb[2][TROWS * 512];      // bf16, XOR-swizzled rows; 2x32KB
    __shared__ float red[2][TROWS][2];        // cross-ph LN partials

    const int t    = threadIdx.x;
    const int w    = t >> 6;
    const int rg   = w & 3;                   // row-group: rows [16rg,16rg+16)
    const int ph   = w >> 2;                  // p-half: p in [64ph, 64ph+64)
    const int lane = t & 63;
    const int cl   = lane & 15;
    const int lg   = lane >> 4;
    const int rowl = rg * 16 + cl;            // this lane's row within tile

    // ---- Wt fragments in registers, loaded once (L2). 4 m x 8 ks = 128 VGPR.
    short8 afrag[4][8];
#pragma unroll
    for (int m = 0; m < 4; m++)
#pragma unroll
        for (int ks = 0; ks < 8; ks++)
            afrag[m][ks] = *(const short8*)(
                Wt + (size_t)(ph * 64 + m * 16 + cl) * Cn + ks * 32 + lg * 8);

    // ---- staging map: thread owns row srow, k in [sk0, sk0+32)
    const int srow = t >> 3;
    const int sk0  = (t & 7) * 32;
    const size_t tile0 = (size_t)blockIdx.x * TPB;

    float4 g[8];
    // prologue: stage tile0 into Fb[0]
    {
        const float* src = F + (tile0 * TROWS + srow) * Cn + sk0;
#pragma unroll
        for (int j = 0; j < 8; j++) g[j] = *(const float4*)(src + j * 4);
#pragma unroll
        for (int q = 0; q < 4; q++) {
            short8 v;
            v[0] = (short)f2bf(g[2*q].x);   v[1] = (short)f2bf(g[2*q].y);
            v[2] = (short)f2bf(g[2*q].z);   v[3] = (short)f2bf(g[2*q].w);
            v[4] = (short)f2bf(g[2*q+1].x); v[5] = (short)f2bf(g[2*q+1].y);
            v[6] = (short)f2bf(g[2*q+1].z); v[7] = (short)f2bf(g[2*q+1].w);
            const int kc = (t & 7) * 4 + q;
            *(short8*)(Fb[0] + srow * 512 + ((kc * 16) ^ ((srow & 7) << 4))) = v;
        }
    }
    __syncthreads();

    int cur = 0;
    for (int ti = 0; ti < TPB; ti++) {
        const size_t tile = tile0 + ti;

        // ---- issue next tile's global loads FIRST (hide under compute)
        if (ti < TPB - 1) {
            const float* src = F + ((tile + 1) * TROWS + srow) * Cn + sk0;
#pragma unroll
            for (int j = 0; j < 8; j++) g[j] = *(const float4*)(src + j * 4);
        }

        // ---- MFMA: pure LDS + registers, no VMEM
        f32x4 acc[4] = {};
#pragma unroll
        for (int ks = 0; ks < 8; ks++) {
            const short8 bf = *(const short8*)(
                Fb[cur] + rowl * 512 + ((ks * 64 + lg * 16) ^ ((cl & 7) << 4)));
#pragma unroll
            for (int m = 0; m < 4; m++)
                acc[m] = __builtin_amdgcn_mfma_f32_16x16x32_bf16(
                    afrag[m][ks], bf, acc[m], 0, 0, 0);
        }
        // lane (cl,lg): acc[m][r] = h[row=rowl][p = ph*64 + m*16 + lg*4 + r]

        // ---- epilogue: bias + LN stats (in-lane + 2 shfl + cross-ph LDS)
        float hv[4][4];
        float s = 0.f, q = 0.f;
#pragma unroll
        for (int m = 0; m < 4; m++) {
            const float4 bb = *(const float4*)(bp + ph * 64 + m * 16 + lg * 4);
#pragma unroll
            for (int r = 0; r < 4; r++) {
                const float h = acc[m][r] + ((const float*)&bb)[r];
                hv[m][r] = h; s += h; q += h * h;
            }
        }
        s += __shfl_xor(s, 16); s += __shfl_xor(s, 32);
        q += __shfl_xor(q, 16); q += __shfl_xor(q, 32);
        if (lg == 0) { red[ph][rowl][0] = s; red[ph][rowl][1] = q; }
        __syncthreads();                                   // B1

        const float st = red[0][rowl][0] + red[1][rowl][0];
        const float qt = red[0][rowl][1] + red[1][rowl][1];
        const float mu  = st * (1.f / Pn);
        const float var = qt * (1.f / Pn) - mu * mu;
        const float inv = rsqrtf(var + LN_EPSf);

        float q2 = 0.f;
#pragma unroll
        for (int m = 0; m < 4; m++) {
            const float4 gg = *(const float4*)(gam + ph * 64 + m * 16 + lg * 4);
            const float4 ee = *(const float4*)(bet + ph * 64 + m * 16 + lg * 4);
#pragma unroll
            for (int r = 0; r < 4; r++) {
                const float hn = (hv[m][r] - mu) * inv * ((const float*)&gg)[r]
                                 + ((const float*)&ee)[r];
                hv[m][r] = hn; q2 += hn * hn;
            }
        }
        q2 += __shfl_xor(q2, 16); q2 += __shfl_xor(q2, 32);
        __syncthreads();                                   // B2 (WAR on red)
        if (lg == 0) red[ph][rowl][0] = q2;
        __syncthreads();                                   // B3

        const float nrm = sqrtf(red[0][rowl][0] + red[1][rowl][0]);
        const float rin = 1.f / fmaxf(nrm, 1e-12f);

        // ---- store: 4 consecutive p per (m) -> one 8B store
        {
            __hip_bfloat16* dst = sem + (tile * TROWS + rowl) * Pn + ph * 64 + lg * 4;
#pragma unroll
            for (int m = 0; m < 4; m++) {
                const unsigned int d0 = (unsigned int)f2bf(hv[m][0] * rin)
                                      | ((unsigned int)f2bf(hv[m][1] * rin) << 16);
                const unsigned int d1 = (unsigned int)f2bf(hv[m][2] * rin)
                                      | ((unsigned int)f2bf(hv[m][3] * rin) << 16);
                uint2 val; val.x = d0; val.y = d1;
                *reinterpret_cast<uint2*>(dst + m * 16) = val;
            }
        }

        // ---- write prefetched tile into the other buffer, swap
        if (ti < TPB - 1) {
#pragma unroll
            for (int q3 = 0; q3 < 4; q3++) {
                short8 v;
                v[0] = (short)f2bf(g[2*q3].x);   v[1] = (short)f2bf(g[2*q3].y);
                v[2] = (short)f2bf(g[2*q3].z);   v[3] = (short)f2bf(g[2*q3].w);
                v[4] = (short)f2bf(g[2*q3+1].x); v[5] = (short)f2bf(g[2*q3+1].y);
                v[6] = (short)f2bf(g[2*q3+1].z); v[7] = (short)f2bf(g[2*q3+1].w);
                const int kc = (t & 7) * 4 + q3;
                *(short8*)(Fb[cur ^ 1] + srow * 512
                           + ((kc * 16) ^ ((srow & 7) << 4))) = v;
            }
            __syncthreads();                               // B4
            cur ^= 1;
        }
    }
}

// ---------------------------------------------------------------------------
// Kernel 2: per-edge semantic dot + spatial sim; outputs FLOAT32.
// 16 lanes per edge, 16 edges per 256-thread block.
__global__ __launch_bounds__(256)
void edge_kernel(const __hip_bfloat16* __restrict__ sem,
                 const float* __restrict__ coords,
                 const int* __restrict__ eidx,
                 const float* __restrict__ alpha,
                 float* __restrict__ out_idx,
                 float* __restrict__ out_w)
{
    const int t   = threadIdx.x;
    const int g   = blockIdx.x * 16 + (t >> 4);   // flat edge id = b*E + e
    const int sub = t & 15;
    const int b   = g / En;

    const int src = eidx[(size_t)g * 2 + 0];
    const int dst = eidx[(size_t)g * 2 + 1];

    const size_t srow = ((size_t)b * Ln + src) * Pn;
    const size_t drow = ((size_t)b * Ln + dst) * Pn;

    const short8 sv = *(const short8*)(sem + srow + sub * 8);
    const short8 dv = *(const short8*)(sem + drow + sub * 8);

    float dotv = 0.f;
#pragma unroll
    for (int j = 0; j < 8; j++)
        dotv = fmaf(bf2f((unsigned short)sv[j]), bf2f((unsigned short)dv[j]), dotv);

    for (int o = 1; o < 16; o <<= 1) dotv += __shfl_xor(dotv, o);

    if (sub == 0) {
        const float a = 1.f / (1.f + expf(-alpha[0]));
        const size_t sc = ((size_t)b * Ln + src) * 2;
        const size_t dc = ((size_t)b * Ln + dst) * 2;
        const float ddx = coords[sc + 0] - coords[dc + 0];
        const float ddy = coords[sc + 1] - coords[dc + 1];
        const float dist = sqrtf(ddx * ddx + ddy * ddy + 1e-8f);
        const float ssim = 1.f - dist / 1.414f;
        const float wgt  = a * dotv + (1.f - a) * ssim;
        out_w[g] = wgt;
        out_idx[(size_t)g * 2 + 0] = (float)src;
        out_idx[(size_t)g * 2 + 1] = (float)dst;
    }
}

extern "C" void kernel_launch(void* const* d_in, const int* in_sizes, int n_in,
                              void* d_out, int out_size, void* d_ws, size_t ws_size,
                              hipStream_t stream) {
    const float* F      = (const float*)d_in[0];   // (B,L,C)
    const float* coords = (const float*)d_in[1];   // (B,L,2)
    const int*   eidx   = (const int*)d_in[2];     // (B,E,2)
    const float* alpha  = (const float*)d_in[3];   // scalar
    const float* Wp     = (const float*)d_in[4];   // (C,P)
    const float* bp     = (const float*)d_in[5];   // (P,)
    const float* gam    = (const float*)d_in[6];   // (P,)
    const float* bet    = (const float*)d_in[7];   // (P,)

    float* out     = (float*)d_out;                 // f32 outputs, concat order:
    float* out_idx = out;                           // edge_index (B,E,2) as f32
    float* out_w   = out + (size_t)Bn * En * 2;     // edge_weights (B,E) as f32

    __hip_bfloat16* Wt  = (__hip_bfloat16*)d_ws;               // 64 KB
    __hip_bfloat16* sem = (__hip_bfloat16*)((char*)d_ws + Cn * Pn * 2); // 32 MB

    wt_prep<<<4, 256, 0, stream>>>(Wp, Wt);
    proj_mfma2<<<(Bn * Ln) / (TROWS * TPB), 512, 0, stream>>>(F, Wt, bp, gam, bet, sem);
    edge_kernel<<<(Bn * En) / 16, 256, 0, stream>>>(sem, coords, eidx, alpha, out_idx, out_w);
}